// Round 14
// baseline (199.462 us; speedup 1.0000x reference)
//
#include <hip/hip_runtime.h>
#include <hip/hip_bf16.h>

// KascadeReuseAttention  B=1, S=2048, DM=1024, H=16, D=64, T=16, NA=3
// Round-14 (base r11/r13 = 162-164us):
//  (1) gemm_qkv retiled 128x128 -> 64x128, grid (24,32)=768 blocks = exactly
//      3/CU (old 384 = 1.5 dispatch-waves, 33% tail on the biggest kernel).
//  (2) attn processes 2 queries (same head, consecutive qi) per wave:
//      attn is latency-bound (VALUBusy~50%, 32 VGPR); two independent
//      dependency chains interleaved double ILP at the stall points.
//      16384 waves remain (16/SIMD) so TLP stays saturated.
// XCD swizzle from r13 dropped (measured neutral).

#define S_LEN 2048
#define DM 1024
#define NH 16
#define HD 64

typedef __bf16 bf16x8 __attribute__((ext_vector_type(8)));
typedef float f32x4 __attribute__((ext_vector_type(4)));

static __device__ __forceinline__ unsigned short f2bf(float f) {
    union { float f; unsigned int i; } un;
    un.f = f;
    unsigned int r = un.i + 0x7FFFu + ((un.i >> 16) & 1u);  // RNE
    return (unsigned short)(r >> 16);
}
static __device__ __forceinline__ float bfu2f(unsigned short u) {
    union { unsigned int i; float f; } un;
    un.i = ((unsigned int)u) << 16;
    return un.f;
}
static __device__ __forceinline__ float bflo(unsigned int u) {
    union { unsigned int i; float f; } un;
    un.i = u << 16;
    return un.f;
}
static __device__ __forceinline__ float bfhi(unsigned int u) {
    union { unsigned int i; float f; } un;
    un.i = u & 0xFFFF0000u;
    return un.f;
}

// async global->LDS, 16 B per lane; LDS dest = uniform base + lane*16.
static __device__ __forceinline__ void gll16(const unsigned short* g,
                                             unsigned short* l) {
    __builtin_amdgcn_global_load_lds(
        (const __attribute__((address_space(1))) unsigned int*)(uintptr_t)g,
        (__attribute__((address_space(3))) unsigned int*)(uintptr_t)l,
        16, 0, 0);
}

// ---------------------------------------------------------------------------
// prep: blocks [0,4096) transpose W* fp32->bf16 [n][k]; blocks [4096,5120)
// convert x fp32->bf16.
// ---------------------------------------------------------------------------
__global__ __launch_bounds__(256) void prep(
    const float* __restrict__ x, unsigned short* __restrict__ xb,
    const float* __restrict__ W0, const float* __restrict__ W1,
    const float* __restrict__ W2, const float* __restrict__ W3,
    unsigned short* __restrict__ T0, unsigned short* __restrict__ T1,
    unsigned short* __restrict__ T2, unsigned short* __restrict__ T3) {
    const int bx = blockIdx.x;
    if (bx < 4096) {
        const int z = bx >> 10, rem = bx & 1023;
        const float* W = (z == 0) ? W0 : (z == 1) ? W1 : (z == 2) ? W2 : W3;
        unsigned short* T = (z == 0) ? T0 : (z == 1) ? T1 : (z == 2) ? T2 : T3;
        __shared__ float t[32][33];
        const int bn = (rem & 31) * 32, bk = (rem >> 5) * 32;
        const int tx = threadIdx.x & 31, ty = threadIdx.x >> 5;
        #pragma unroll
        for (int m = 0; m < 4; ++m)
            t[ty + m * 8][tx] = W[(size_t)(bk + ty + m * 8) * 1024 + bn + tx];
        __syncthreads();
        #pragma unroll
        for (int m = 0; m < 4; ++m)
            T[(size_t)(bn + ty + m * 8) * 1024 + bk + tx] = f2bf(t[tx][ty + m * 8]);
    } else {
        const int i = (bx - 4096) * 2048 + threadIdx.x * 8;
        float4 f0 = *(const float4*)(x + i);
        float4 f1 = *(const float4*)(x + i + 4);
        ushort4 o0, o1;
        o0.x = f2bf(f0.x); o0.y = f2bf(f0.y); o0.z = f2bf(f0.z); o0.w = f2bf(f0.w);
        o1.x = f2bf(f1.x); o1.y = f2bf(f1.y); o1.z = f2bf(f1.z); o1.w = f2bf(f1.w);
        *(ushort4*)(xb + i) = o0;
        *(ushort4*)(xb + i + 4) = o1;
    }
}

// ---------------------------------------------------------------------------
// QKV GEMM: 64x128 tile, BK=32, grid (24,32) = 768 blocks (3/CU, no tail),
// global_load_lds width-16 staging. Fused RoPE epilogue, head-major bf16
// out [H][S][64].
// ---------------------------------------------------------------------------
__global__ __launch_bounds__(256) void gemm_qkv(
    const unsigned short* __restrict__ xb,
    const unsigned short* __restrict__ Wtq, const unsigned short* __restrict__ Wtk,
    const unsigned short* __restrict__ Wtv,
    unsigned short* __restrict__ qh, unsigned short* __restrict__ kh,
    unsigned short* __restrict__ vh,
    const float* __restrict__ cs, const float* __restrict__ sn) {
    __shared__ __align__(16) unsigned short Al[64 * 32];
    __shared__ __align__(16) unsigned short Bl[128 * 32];
    const int tid = threadIdx.x;
    const int nb = blockIdx.x >> 3;
    const unsigned short* __restrict__ Bt = (nb == 0) ? Wtq : (nb == 1) ? Wtk : Wtv;
    unsigned short* __restrict__ OUT = (nb == 0) ? qh : (nb == 1) ? kh : vh;
    const int col0 = (blockIdx.x & 7) * 128;
    const int row0 = blockIdx.y * 64;
    const int lane = tid & 63, wvi = tid >> 6;
    const int wr = (wvi >> 1) * 32, wc = (wvi & 1) * 64;
    const int l15 = lane & 15, quad = lane >> 4;

    const int grow = lane >> 2;            // 0..15
    const int gkc = (lane & 3) * 8;        // element offset within row
    const unsigned short* gA = xb + (size_t)(row0 + wvi * 16 + grow) * 1024 + gkc;
    const unsigned short* gB = Bt + (size_t)(col0 + wvi * 32 + grow) * 1024 + gkc;
    unsigned short* lA = Al + (wvi * 16) * 32;   // wave-uniform LDS base
    unsigned short* lB = Bl + (wvi * 32) * 32;

    f32x4 acc[2][4] = {};
    for (int k0 = 0; k0 < 1024; k0 += 32) {
        __syncthreads();  // prior iter's ds_reads complete before overwrite
        gll16(gA + k0, lA);                       // A: 64 rows total
        gll16(gB + k0, lB);                       // B: 128 rows total
        gll16(gB + 16 * 1024 + k0, lB + 16 * 32);
        __syncthreads();  // drains vmcnt(0): GLL data landed
        bf16x8 af[2], bfr[4];
        #pragma unroll
        for (int i = 0; i < 2; ++i)
            af[i] = *(const bf16x8*)&Al[(wr + i * 16 + l15) * 32 + quad * 8];
        #pragma unroll
        for (int j = 0; j < 4; ++j)
            bfr[j] = *(const bf16x8*)&Bl[(wc + j * 16 + l15) * 32 + quad * 8];
        #pragma unroll
        for (int i = 0; i < 2; ++i)
            #pragma unroll
            for (int j = 0; j < 4; ++j)
                acc[i][j] = __builtin_amdgcn_mfma_f32_16x16x32_bf16(
                    af[i], bfr[j], acc[i][j], 0, 0, 0);
    }

    // epilogue: wave's 64 cols = one head; fused RoPE; head-major store
    const int hh = ((blockIdx.x & 7) << 1) + (wc >> 6);
    const bool dorope = (nb != 2);
    #pragma unroll
    for (int i = 0; i < 2; ++i) {
        const int rowb = row0 + wr + i * 16 + quad * 4;
        #pragma unroll
        for (int r = 0; r < 4; ++r) {
            const int s = rowb + r;
            float v0 = acc[i][0][r], v1 = acc[i][1][r];
            float v2 = acc[i][2][r], v3 = acc[i][3][r];
            if (dorope) {
                float c0 = cs[s * 32 + l15],      s0 = sn[s * 32 + l15];
                float c1 = cs[s * 32 + 16 + l15], s1 = sn[s * 32 + 16 + l15];
                float lo0 = v0 * c0 - v2 * s0;
                float hi0 = v2 * c0 + v0 * s0;
                float lo1 = v1 * c1 - v3 * s1;
                float hi1 = v3 * c1 + v1 * s1;
                v0 = lo0; v1 = lo1; v2 = hi0; v3 = hi1;
            }
            unsigned short* op = OUT + (size_t)hh * (S_LEN * 64) + (size_t)s * 64 + l15;
            op[0]  = f2bf(v0);
            op[16] = f2bf(v1);
            op[32] = f2bf(v2);
            op[48] = f2bf(v3);
        }
    }
}

// ---------------------------------------------------------------------------
// Attention: one wave per TWO queries (same head, qi and qi+1) -> 2x ILP on
// the latency-bound chains. Wave-private LDS slices [2 queries][64];
// same-address broadcast ds_reads; phase-4 addresses from ts (early).
// Grid 4096 blocks x 4 waves x 2 queries = 32768 (h,q) pairs.
// ---------------------------------------------------------------------------
__global__ __launch_bounds__(256) void attn_kernel(
    const unsigned short* __restrict__ qh, const unsigned short* __restrict__ kh,
    const unsigned short* __restrict__ vh, const int* __restrict__ anc,
    unsigned short* __restrict__ att) {
    __shared__ __align__(16) float qs[4][128];
    __shared__ __align__(16) int   ts[4][128];
    __shared__ __align__(16) float ws[4][128];
    const int w4 = threadIdx.x >> 6;
    const int lane = threadIdx.x & 63;
    const int base = blockIdx.x * 8 + w4 * 2;   // first wid of this wave
    const int h = base >> 11;                   // 2048/head, 8 | 2048 -> uniform
    const int qi0 = base & 2047;
    const int qi1 = qi0 + 1;
    const size_t hb = (size_t)h * (S_LEN * 64);

    // phase 1: stage q + tokens for both queries
    const float q_own0 = bfu2f(qh[hb + (size_t)qi0 * 64 + lane]);
    const float q_own1 = bfu2f(qh[hb + (size_t)qi1 * 64 + lane]);
    const int slot = lane >> 4;
    const int tile0 = (slot < 3) ? anc[((size_t)h * S_LEN + qi0) * 3 + slot]
                                 : (qi0 >> 4);
    const int tile1 = (slot < 3) ? anc[((size_t)h * S_LEN + qi1) * 3 + slot]
                                 : (qi1 >> 4);
    const int tok0 = tile0 * 16 + (lane & 15);
    const int tok1 = tile1 * 16 + (lane & 15);
    qs[w4][lane] = q_own0;        qs[w4][64 + lane] = q_own1;
    ts[w4][lane] = tok0;          ts[w4][64 + lane] = tok1;

    const int c = lane & 3;
    const int t = lane >> 2;
    float qv0[16], qv1[16];
    #pragma unroll
    for (int r = 0; r < 4; ++r) {
        float4 f0 = *(const float4*)&qs[w4][c * 16 + r * 4];
        float4 f1 = *(const float4*)&qs[w4][64 + c * 16 + r * 4];
        qv0[r * 4 + 0] = f0.x; qv0[r * 4 + 1] = f0.y;
        qv0[r * 4 + 2] = f0.z; qv0[r * 4 + 3] = f0.w;
        qv1[r * 4 + 0] = f1.x; qv1[r * 4 + 1] = f1.y;
        qv1[r * 4 + 2] = f1.z; qv1[r * 4 + 3] = f1.w;
    }

    // phase 2: 4 lanes/token, two independent chains per pass
    #pragma unroll
    for (int p = 0; p < 4; ++p) {
        const int tk0 = ts[w4][p * 16 + t];
        const int tk1 = ts[w4][64 + p * 16 + t];
        const unsigned short* kp0 = kh + hb + (size_t)tk0 * 64 + c * 16;
        const unsigned short* kp1 = kh + hb + (size_t)tk1 * 64 + c * 16;
        const uint4 a0 = *(const uint4*)kp0;
        const uint4 a1 = *(const uint4*)(kp0 + 8);
        const uint4 b0 = *(const uint4*)kp1;
        const uint4 b1 = *(const uint4*)(kp1 + 8);
        float p0, p1;
        p0 = bflo(a0.x) * qv0[0];
        p1 = bflo(b0.x) * qv1[0];
        p0 = fmaf(bfhi(a0.x), qv0[1], p0);  p1 = fmaf(bfhi(b0.x), qv1[1], p1);
        p0 = fmaf(bflo(a0.y), qv0[2], p0);  p1 = fmaf(bflo(b0.y), qv1[2], p1);
        p0 = fmaf(bfhi(a0.y), qv0[3], p0);  p1 = fmaf(bfhi(b0.y), qv1[3], p1);
        p0 = fmaf(bflo(a0.z), qv0[4], p0);  p1 = fmaf(bflo(b0.z), qv1[4], p1);
        p0 = fmaf(bfhi(a0.z), qv0[5], p0);  p1 = fmaf(bfhi(b0.z), qv1[5], p1);
        p0 = fmaf(bflo(a0.w), qv0[6], p0);  p1 = fmaf(bflo(b0.w), qv1[6], p1);
        p0 = fmaf(bfhi(a0.w), qv0[7], p0);  p1 = fmaf(bfhi(b0.w), qv1[7], p1);
        p0 = fmaf(bflo(a1.x), qv0[8], p0);  p1 = fmaf(bflo(b1.x), qv1[8], p1);
        p0 = fmaf(bfhi(a1.x), qv0[9], p0);  p1 = fmaf(bfhi(b1.x), qv1[9], p1);
        p0 = fmaf(bflo(a1.y), qv0[10], p0); p1 = fmaf(bflo(b1.y), qv1[10], p1);
        p0 = fmaf(bfhi(a1.y), qv0[11], p0); p1 = fmaf(bfhi(b1.y), qv1[11], p1);
        p0 = fmaf(bflo(a1.z), qv0[12], p0); p1 = fmaf(bflo(b1.z), qv1[12], p1);
        p0 = fmaf(bfhi(a1.z), qv0[13], p0); p1 = fmaf(bfhi(b1.z), qv1[13], p1);
        p0 = fmaf(bflo(a1.w), qv0[14], p0); p1 = fmaf(bflo(b1.w), qv1[14], p1);
        p0 = fmaf(bfhi(a1.w), qv0[15], p0); p1 = fmaf(bfhi(b1.w), qv1[15], p1);
        p0 += __shfl_xor(p0, 1, 64);  p1 += __shfl_xor(p1, 1, 64);
        p0 += __shfl_xor(p0, 2, 64);  p1 += __shfl_xor(p1, 2, 64);
        if (c == 0) {
            ws[w4][p * 16 + t] = p0;
            ws[w4][64 + p * 16 + t] = p1;
        }
    }

    // phase 3: two interleaved wave softmaxes
    float lg0 = ws[w4][lane];
    float lg1 = ws[w4][64 + lane];
    const bool fut0 = tok0 > qi0;
    const bool fut1 = tok1 > qi1;
    lg0 = fut0 ? -1e30f : lg0 * 0.125f;
    lg1 = fut1 ? -1e30f : lg1 * 0.125f;
    float m0 = lg0, m1 = lg1;
    #pragma unroll
    for (int off = 32; off >= 1; off >>= 1) {
        m0 = fmaxf(m0, __shfl_xor(m0, off, 64));
        m1 = fmaxf(m1, __shfl_xor(m1, off, 64));
    }
    const float e0 = fut0 ? 0.f : __expf(lg0 - m0);
    const float e1 = fut1 ? 0.f : __expf(lg1 - m1);
    float s0 = e0, s1 = e1;
    #pragma unroll
    for (int off = 32; off >= 1; off >>= 1) {
        s0 += __shfl_xor(s0, off, 64);
        s1 += __shfl_xor(s1, off, 64);
    }
    ws[w4][lane] = e0 / s0;
    ws[w4][64 + lane] = e1 / s1;

    // phase 4: lane = dim; two interleaved 8-deep gather/FMA chains
    const unsigned short* vb = vh + hb + lane;
    float out0 = 0.f, out1 = 0.f;
    #pragma unroll
    for (int kk = 0; kk < 64; kk += 8) {
        const int4 ta0 = *(const int4*)&ts[w4][kk];
        const int4 tb0 = *(const int4*)&ts[w4][kk + 4];
        const int4 ta1 = *(const int4*)&ts[w4][64 + kk];
        const int4 tb1 = *(const int4*)&ts[w4][64 + kk + 4];
        const float a0 = bfu2f(vb[(size_t)ta0.x * 64]);
        const float a1 = bfu2f(vb[(size_t)ta0.y * 64]);
        const float a2 = bfu2f(vb[(size_t)ta0.z * 64]);
        const float a3 = bfu2f(vb[(size_t)ta0.w * 64]);
        const float a4 = bfu2f(vb[(size_t)tb0.x * 64]);
        const float a5 = bfu2f(vb[(size_t)tb0.y * 64]);
        const float a6 = bfu2f(vb[(size_t)tb0.z * 64]);
        const float a7 = bfu2f(vb[(size_t)tb0.w * 64]);
        const float b0 = bfu2f(vb[(size_t)ta1.x * 64]);
        const float b1 = bfu2f(vb[(size_t)ta1.y * 64]);
        const float b2 = bfu2f(vb[(size_t)ta1.z * 64]);
        const float b3 = bfu2f(vb[(size_t)ta1.w * 64]);
        const float b4 = bfu2f(vb[(size_t)tb1.x * 64]);
        const float b5 = bfu2f(vb[(size_t)tb1.y * 64]);
        const float b6 = bfu2f(vb[(size_t)tb1.z * 64]);
        const float b7 = bfu2f(vb[(size_t)tb1.w * 64]);
        const float4 wa0 = *(const float4*)&ws[w4][kk];
        const float4 wb0 = *(const float4*)&ws[w4][kk + 4];
        const float4 wa1 = *(const float4*)&ws[w4][64 + kk];
        const float4 wb1 = *(const float4*)&ws[w4][64 + kk + 4];
        out0 = fmaf(wa0.x, a0, out0);  out1 = fmaf(wa1.x, b0, out1);
        out0 = fmaf(wa0.y, a1, out0);  out1 = fmaf(wa1.y, b1, out1);
        out0 = fmaf(wa0.z, a2, out0);  out1 = fmaf(wa1.z, b2, out1);
        out0 = fmaf(wa0.w, a3, out0);  out1 = fmaf(wa1.w, b3, out1);
        out0 = fmaf(wb0.x, a4, out0);  out1 = fmaf(wb1.x, b4, out1);
        out0 = fmaf(wb0.y, a5, out0);  out1 = fmaf(wb1.y, b5, out1);
        out0 = fmaf(wb0.z, a6, out0);  out1 = fmaf(wb1.z, b6, out1);
        out0 = fmaf(wb0.w, a7, out0);  out1 = fmaf(wb1.w, b7, out1);
    }
    att[(size_t)qi0 * DM + h * HD + lane] = f2bf(out0);
    att[(size_t)qi1 * DM + h * HD + lane] = f2bf(out1);
}

// ---------------------------------------------------------------------------
// Out GEMM: 64x128 tile, grid (8,32), global_load_lds staging.
// ---------------------------------------------------------------------------
__global__ __launch_bounds__(256) void gemm_out(
    const unsigned short* __restrict__ A, const unsigned short* __restrict__ Bt,
    float* __restrict__ C) {
    __shared__ __align__(16) unsigned short Al[64 * 32];
    __shared__ __align__(16) unsigned short Bl[128 * 32];
    const int tid = threadIdx.x;
    const int col0 = blockIdx.x * 128;
    const int row0 = blockIdx.y * 64;
    const int lane = tid & 63, wvi = tid >> 6;
    const int wr = (wvi >> 1) * 32, wc = (wvi & 1) * 64;
    const int l15 = lane & 15, quad = lane >> 4;

    const int grow = lane >> 2;
    const int gkc = (lane & 3) * 8;
    const unsigned short* gA = A + (size_t)(row0 + wvi * 16 + grow) * 1024 + gkc;
    const unsigned short* gB = Bt + (size_t)(col0 + wvi * 32 + grow) * 1024 + gkc;
    unsigned short* lA = Al + (wvi * 16) * 32;   // wave-uniform
    unsigned short* lB = Bl + (wvi * 32) * 32;

    f32x4 acc[2][4] = {};
    for (int k0 = 0; k0 < 1024; k0 += 32) {
        __syncthreads();
        gll16(gA + k0, lA);                       // A: 64 rows total
        gll16(gB + k0, lB);                       // B: 128 rows total
        gll16(gB + 16 * 1024 + k0, lB + 16 * 32);
        __syncthreads();
        bf16x8 af[2], bfr[4];
        #pragma unroll
        for (int i = 0; i < 2; ++i)
            af[i] = *(const bf16x8*)&Al[(wr + i * 16 + l15) * 32 + quad * 8];
        #pragma unroll
        for (int j = 0; j < 4; ++j)
            bfr[j] = *(const bf16x8*)&Bl[(wc + j * 16 + l15) * 32 + quad * 8];
        #pragma unroll
        for (int i = 0; i < 2; ++i)
            #pragma unroll
            for (int j = 0; j < 4; ++j)
                acc[i][j] = __builtin_amdgcn_mfma_f32_16x16x32_bf16(
                    af[i], bfr[j], acc[i][j], 0, 0, 0);
    }
    #pragma unroll
    for (int i = 0; i < 2; ++i) {
        const int rowb = row0 + wr + i * 16 + quad * 4;
        #pragma unroll
        for (int r = 0; r < 4; ++r) {
            float* crow = C + (size_t)(rowb + r) * 1024 + col0 + wc;
            #pragma unroll
            for (int j = 0; j < 4; ++j)
                crow[j * 16 + l15] = acc[i][j][r];
        }
    }
}

// ---------------------------------------------------------------------------
extern "C" void kernel_launch(void* const* d_in, const int* in_sizes, int n_in,
                              void* d_out, int out_size, void* d_ws, size_t ws_size,
                              hipStream_t stream) {
    const float* x   = (const float*)d_in[0];
    const float* Wq  = (const float*)d_in[1];
    const float* Wk  = (const float*)d_in[2];
    const float* Wv  = (const float*)d_in[3];
    const float* Wo  = (const float*)d_in[4];
    const float* cs  = (const float*)d_in[5];
    const float* sn  = (const float*)d_in[6];
    const int*   anc = (const int*)d_in[7];
    float* out = (float*)d_out;

    unsigned short* xb  = (unsigned short*)d_ws;
    unsigned short* Wtq = xb  + (size_t)2048 * 1024;
    unsigned short* Wtk = Wtq + (size_t)1024 * 1024;
    unsigned short* Wtv = Wtk + (size_t)1024 * 1024;
    unsigned short* Wto = Wtv + (size_t)1024 * 1024;
    unsigned short* qh  = Wto + (size_t)1024 * 1024;   // [H][S][64]
    unsigned short* kh  = qh  + (size_t)2048 * 1024;
    unsigned short* vh  = kh  + (size_t)2048 * 1024;
    unsigned short* att = vh  + (size_t)2048 * 1024;   // [S][H*D]

    prep<<<5120, 256, 0, stream>>>(x, xb, Wq, Wk, Wv, Wo, Wtq, Wtk, Wtv, Wto);
    gemm_qkv<<<dim3(24, 32), 256, 0, stream>>>(xb, Wtq, Wtk, Wtv,
                                               qh, kh, vh, cs, sn);
    attn_kernel<<<(S_LEN * NH) / 8, 256, 0, stream>>>(qh, kh, vh, anc, att);
    gemm_out<<<dim3(8, 32), 256, 0, stream>>>(att, Wto, out);
}

// Round 15
// 157.713 us; speedup vs baseline: 1.2647x; 1.2647x over previous
//
#include <hip/hip_runtime.h>
#include <hip/hip_bf16.h>

// KascadeReuseAttention  B=1, S=2048, DM=1024, H=16, D=64, T=16, NA=3
// Round-15: recombination of best-measured pieces. r14's attn 2-query
// experiment regressed 2x (VGPR_Count=36 << the 32+ live values needed ->
// compiler demoted the doubled working set; half TLP, no ILP gain). attn
// reverted to r8-verbatim (3rd failed restructure -- it is a local optimum:
// early addresses + low reg pressure + max TLP). Kept from r14: qkv 64x128
// retile, 768 blocks = 3/CU no-tail (r14 delta decomposition: ~ -3us).
// Structure: prep + qkv(GLL) + attn(r8) + out(GLL), 4 launches.

#define S_LEN 2048
#define DM 1024
#define NH 16
#define HD 64

typedef __bf16 bf16x8 __attribute__((ext_vector_type(8)));
typedef float f32x4 __attribute__((ext_vector_type(4)));

static __device__ __forceinline__ unsigned short f2bf(float f) {
    union { float f; unsigned int i; } un;
    un.f = f;
    unsigned int r = un.i + 0x7FFFu + ((un.i >> 16) & 1u);  // RNE
    return (unsigned short)(r >> 16);
}
static __device__ __forceinline__ float bfu2f(unsigned short u) {
    union { unsigned int i; float f; } un;
    un.i = ((unsigned int)u) << 16;
    return un.f;
}
static __device__ __forceinline__ float bflo(unsigned int u) {
    union { unsigned int i; float f; } un;
    un.i = u << 16;
    return un.f;
}
static __device__ __forceinline__ float bfhi(unsigned int u) {
    union { unsigned int i; float f; } un;
    un.i = u & 0xFFFF0000u;
    return un.f;
}

// async global->LDS, 16 B per lane; LDS dest = uniform base + lane*16.
static __device__ __forceinline__ void gll16(const unsigned short* g,
                                             unsigned short* l) {
    __builtin_amdgcn_global_load_lds(
        (const __attribute__((address_space(1))) unsigned int*)(uintptr_t)g,
        (__attribute__((address_space(3))) unsigned int*)(uintptr_t)l,
        16, 0, 0);
}

// ---------------------------------------------------------------------------
// prep: blocks [0,4096) transpose W* fp32->bf16 [n][k]; blocks [4096,5120)
// convert x fp32->bf16.
// ---------------------------------------------------------------------------
__global__ __launch_bounds__(256) void prep(
    const float* __restrict__ x, unsigned short* __restrict__ xb,
    const float* __restrict__ W0, const float* __restrict__ W1,
    const float* __restrict__ W2, const float* __restrict__ W3,
    unsigned short* __restrict__ T0, unsigned short* __restrict__ T1,
    unsigned short* __restrict__ T2, unsigned short* __restrict__ T3) {
    const int bx = blockIdx.x;
    if (bx < 4096) {
        const int z = bx >> 10, rem = bx & 1023;
        const float* W = (z == 0) ? W0 : (z == 1) ? W1 : (z == 2) ? W2 : W3;
        unsigned short* T = (z == 0) ? T0 : (z == 1) ? T1 : (z == 2) ? T2 : T3;
        __shared__ float t[32][33];
        const int bn = (rem & 31) * 32, bk = (rem >> 5) * 32;
        const int tx = threadIdx.x & 31, ty = threadIdx.x >> 5;
        #pragma unroll
        for (int m = 0; m < 4; ++m)
            t[ty + m * 8][tx] = W[(size_t)(bk + ty + m * 8) * 1024 + bn + tx];
        __syncthreads();
        #pragma unroll
        for (int m = 0; m < 4; ++m)
            T[(size_t)(bn + ty + m * 8) * 1024 + bk + tx] = f2bf(t[tx][ty + m * 8]);
    } else {
        const int i = (bx - 4096) * 2048 + threadIdx.x * 8;
        float4 f0 = *(const float4*)(x + i);
        float4 f1 = *(const float4*)(x + i + 4);
        ushort4 o0, o1;
        o0.x = f2bf(f0.x); o0.y = f2bf(f0.y); o0.z = f2bf(f0.z); o0.w = f2bf(f0.w);
        o1.x = f2bf(f1.x); o1.y = f2bf(f1.y); o1.z = f2bf(f1.z); o1.w = f2bf(f1.w);
        *(ushort4*)(xb + i) = o0;
        *(ushort4*)(xb + i + 4) = o1;
    }
}

// ---------------------------------------------------------------------------
// QKV GEMM: 64x128 tile, BK=32, grid (24,32) = 768 blocks (3/CU, no tail),
// global_load_lds width-16 staging. Fused RoPE epilogue, head-major bf16
// out [H][S][64].
// ---------------------------------------------------------------------------
__global__ __launch_bounds__(256) void gemm_qkv(
    const unsigned short* __restrict__ xb,
    const unsigned short* __restrict__ Wtq, const unsigned short* __restrict__ Wtk,
    const unsigned short* __restrict__ Wtv,
    unsigned short* __restrict__ qh, unsigned short* __restrict__ kh,
    unsigned short* __restrict__ vh,
    const float* __restrict__ cs, const float* __restrict__ sn) {
    __shared__ __align__(16) unsigned short Al[64 * 32];
    __shared__ __align__(16) unsigned short Bl[128 * 32];
    const int tid = threadIdx.x;
    const int nb = blockIdx.x >> 3;
    const unsigned short* __restrict__ Bt = (nb == 0) ? Wtq : (nb == 1) ? Wtk : Wtv;
    unsigned short* __restrict__ OUT = (nb == 0) ? qh : (nb == 1) ? kh : vh;
    const int col0 = (blockIdx.x & 7) * 128;
    const int row0 = blockIdx.y * 64;
    const int lane = tid & 63, wvi = tid >> 6;
    const int wr = (wvi >> 1) * 32, wc = (wvi & 1) * 64;
    const int l15 = lane & 15, quad = lane >> 4;

    const int grow = lane >> 2;            // 0..15
    const int gkc = (lane & 3) * 8;        // element offset within row
    const unsigned short* gA = xb + (size_t)(row0 + wvi * 16 + grow) * 1024 + gkc;
    const unsigned short* gB = Bt + (size_t)(col0 + wvi * 32 + grow) * 1024 + gkc;
    unsigned short* lA = Al + (wvi * 16) * 32;   // wave-uniform LDS base
    unsigned short* lB = Bl + (wvi * 32) * 32;

    f32x4 acc[2][4] = {};
    for (int k0 = 0; k0 < 1024; k0 += 32) {
        __syncthreads();  // prior iter's ds_reads complete before overwrite
        gll16(gA + k0, lA);                       // A: 64 rows total
        gll16(gB + k0, lB);                       // B: 128 rows total
        gll16(gB + 16 * 1024 + k0, lB + 16 * 32);
        __syncthreads();  // drains vmcnt(0): GLL data landed
        bf16x8 af[2], bfr[4];
        #pragma unroll
        for (int i = 0; i < 2; ++i)
            af[i] = *(const bf16x8*)&Al[(wr + i * 16 + l15) * 32 + quad * 8];
        #pragma unroll
        for (int j = 0; j < 4; ++j)
            bfr[j] = *(const bf16x8*)&Bl[(wc + j * 16 + l15) * 32 + quad * 8];
        #pragma unroll
        for (int i = 0; i < 2; ++i)
            #pragma unroll
            for (int j = 0; j < 4; ++j)
                acc[i][j] = __builtin_amdgcn_mfma_f32_16x16x32_bf16(
                    af[i], bfr[j], acc[i][j], 0, 0, 0);
    }

    // epilogue: wave's 64 cols = one head; fused RoPE; head-major store
    const int hh = ((blockIdx.x & 7) << 1) + (wc >> 6);
    const bool dorope = (nb != 2);
    #pragma unroll
    for (int i = 0; i < 2; ++i) {
        const int rowb = row0 + wr + i * 16 + quad * 4;
        #pragma unroll
        for (int r = 0; r < 4; ++r) {
            const int s = rowb + r;
            float v0 = acc[i][0][r], v1 = acc[i][1][r];
            float v2 = acc[i][2][r], v3 = acc[i][3][r];
            if (dorope) {
                float c0 = cs[s * 32 + l15],      s0 = sn[s * 32 + l15];
                float c1 = cs[s * 32 + 16 + l15], s1 = sn[s * 32 + 16 + l15];
                float lo0 = v0 * c0 - v2 * s0;
                float hi0 = v2 * c0 + v0 * s0;
                float lo1 = v1 * c1 - v3 * s1;
                float hi1 = v3 * c1 + v1 * s1;
                v0 = lo0; v1 = lo1; v2 = hi0; v3 = hi1;
            }
            unsigned short* op = OUT + (size_t)hh * (S_LEN * 64) + (size_t)s * 64 + l15;
            op[0]  = f2bf(v0);
            op[16] = f2bf(v1);
            op[32] = f2bf(v2);
            op[48] = f2bf(v3);
        }
    }
}

// ---------------------------------------------------------------------------
// Attention (r8-verbatim, frozen): one wave per (h,q). Wave-private LDS
// slices; same-address broadcast ds_reads; phase-4 addresses from ts
// (written phase 1) so v-loads issue under the softmax chain.
// ---------------------------------------------------------------------------
__global__ __launch_bounds__(256) void attn_kernel(
    const unsigned short* __restrict__ qh, const unsigned short* __restrict__ kh,
    const unsigned short* __restrict__ vh, const int* __restrict__ anc,
    unsigned short* __restrict__ att) {
    __shared__ __align__(16) float qs[4][64];
    __shared__ __align__(16) int   ts[4][64];
    __shared__ __align__(16) float ws[4][64];
    const int w4 = threadIdx.x >> 6;
    const int lane = threadIdx.x & 63;
    const int wid = (blockIdx.x << 2) + w4;
    const int h = wid >> 11;
    const int qi = wid & 2047;
    const size_t hb = (size_t)h * (S_LEN * 64);

    const float q_own = bfu2f(qh[hb + (size_t)qi * 64 + lane]);
    const int slot = lane >> 4;
    const int tile = (slot < 3) ? anc[((size_t)h * S_LEN + qi) * 3 + slot]
                                : (qi >> 4);
    const int tok_own = tile * 16 + (lane & 15);
    qs[w4][lane] = q_own;
    ts[w4][lane] = tok_own;

    const int c = lane & 3;
    const int t = lane >> 2;
    float qv[16];
    #pragma unroll
    for (int r = 0; r < 4; ++r) {
        float4 f = *(const float4*)&qs[w4][c * 16 + r * 4];
        qv[r * 4 + 0] = f.x; qv[r * 4 + 1] = f.y;
        qv[r * 4 + 2] = f.z; qv[r * 4 + 3] = f.w;
    }

    #pragma unroll
    for (int p = 0; p < 4; ++p) {
        const int tk = ts[w4][p * 16 + t];
        const unsigned short* kp = kh + hb + (size_t)tk * 64 + c * 16;
        const uint4 k0 = *(const uint4*)kp;
        const uint4 k1 = *(const uint4*)(kp + 8);
        float part;
        part = bflo(k0.x) * qv[0];
        part = fmaf(bfhi(k0.x), qv[1], part);
        part = fmaf(bflo(k0.y), qv[2], part);
        part = fmaf(bfhi(k0.y), qv[3], part);
        part = fmaf(bflo(k0.z), qv[4], part);
        part = fmaf(bfhi(k0.z), qv[5], part);
        part = fmaf(bflo(k0.w), qv[6], part);
        part = fmaf(bfhi(k0.w), qv[7], part);
        part = fmaf(bflo(k1.x), qv[8], part);
        part = fmaf(bfhi(k1.x), qv[9], part);
        part = fmaf(bflo(k1.y), qv[10], part);
        part = fmaf(bfhi(k1.y), qv[11], part);
        part = fmaf(bflo(k1.z), qv[12], part);
        part = fmaf(bfhi(k1.z), qv[13], part);
        part = fmaf(bflo(k1.w), qv[14], part);
        part = fmaf(bfhi(k1.w), qv[15], part);
        part += __shfl_xor(part, 1, 64);
        part += __shfl_xor(part, 2, 64);
        if (c == 0) ws[w4][p * 16 + t] = part;
    }

    float logit = ws[w4][lane];
    const bool fut = tok_own > qi;
    logit = fut ? -1e30f : logit * 0.125f;

    float m = logit;
    #pragma unroll
    for (int off = 32; off >= 1; off >>= 1)
        m = fmaxf(m, __shfl_xor(m, off, 64));
    const float e = fut ? 0.f : __expf(logit - m);
    float ssum = e;
    #pragma unroll
    for (int off = 32; off >= 1; off >>= 1)
        ssum += __shfl_xor(ssum, off, 64);
    ws[w4][lane] = e / ssum;

    const unsigned short* vb = vh + hb + lane;
    float out = 0.f;
    #pragma unroll
    for (int kk = 0; kk < 64; kk += 8) {
        const int4 ta = *(const int4*)&ts[w4][kk];
        const int4 tb = *(const int4*)&ts[w4][kk + 4];
        const float v0 = bfu2f(vb[(size_t)ta.x * 64]);
        const float v1 = bfu2f(vb[(size_t)ta.y * 64]);
        const float v2 = bfu2f(vb[(size_t)ta.z * 64]);
        const float v3 = bfu2f(vb[(size_t)ta.w * 64]);
        const float v4 = bfu2f(vb[(size_t)tb.x * 64]);
        const float v5 = bfu2f(vb[(size_t)tb.y * 64]);
        const float v6 = bfu2f(vb[(size_t)tb.z * 64]);
        const float v7 = bfu2f(vb[(size_t)tb.w * 64]);
        const float4 wa = *(const float4*)&ws[w4][kk];
        const float4 wb = *(const float4*)&ws[w4][kk + 4];
        out = fmaf(wa.x, v0, out);
        out = fmaf(wa.y, v1, out);
        out = fmaf(wa.z, v2, out);
        out = fmaf(wa.w, v3, out);
        out = fmaf(wb.x, v4, out);
        out = fmaf(wb.y, v5, out);
        out = fmaf(wb.z, v6, out);
        out = fmaf(wb.w, v7, out);
    }
    att[(size_t)qi * DM + h * HD + lane] = f2bf(out);
}

// ---------------------------------------------------------------------------
// Out GEMM: 64x128 tile, grid (8,32), global_load_lds staging.
// ---------------------------------------------------------------------------
__global__ __launch_bounds__(256) void gemm_out(
    const unsigned short* __restrict__ A, const unsigned short* __restrict__ Bt,
    float* __restrict__ C) {
    __shared__ __align__(16) unsigned short Al[64 * 32];
    __shared__ __align__(16) unsigned short Bl[128 * 32];
    const int tid = threadIdx.x;
    const int col0 = blockIdx.x * 128;
    const int row0 = blockIdx.y * 64;
    const int lane = tid & 63, wvi = tid >> 6;
    const int wr = (wvi >> 1) * 32, wc = (wvi & 1) * 64;
    const int l15 = lane & 15, quad = lane >> 4;

    const int grow = lane >> 2;
    const int gkc = (lane & 3) * 8;
    const unsigned short* gA = A + (size_t)(row0 + wvi * 16 + grow) * 1024 + gkc;
    const unsigned short* gB = Bt + (size_t)(col0 + wvi * 32 + grow) * 1024 + gkc;
    unsigned short* lA = Al + (wvi * 16) * 32;   // wave-uniform
    unsigned short* lB = Bl + (wvi * 32) * 32;

    f32x4 acc[2][4] = {};
    for (int k0 = 0; k0 < 1024; k0 += 32) {
        __syncthreads();
        gll16(gA + k0, lA);                       // A: 64 rows total
        gll16(gB + k0, lB);                       // B: 128 rows total
        gll16(gB + 16 * 1024 + k0, lB + 16 * 32);
        __syncthreads();
        bf16x8 af[2], bfr[4];
        #pragma unroll
        for (int i = 0; i < 2; ++i)
            af[i] = *(const bf16x8*)&Al[(wr + i * 16 + l15) * 32 + quad * 8];
        #pragma unroll
        for (int j = 0; j < 4; ++j)
            bfr[j] = *(const bf16x8*)&Bl[(wc + j * 16 + l15) * 32 + quad * 8];
        #pragma unroll
        for (int i = 0; i < 2; ++i)
            #pragma unroll
            for (int j = 0; j < 4; ++j)
                acc[i][j] = __builtin_amdgcn_mfma_f32_16x16x32_bf16(
                    af[i], bfr[j], acc[i][j], 0, 0, 0);
    }
    #pragma unroll
    for (int i = 0; i < 2; ++i) {
        const int rowb = row0 + wr + i * 16 + quad * 4;
        #pragma unroll
        for (int r = 0; r < 4; ++r) {
            float* crow = C + (size_t)(rowb + r) * 1024 + col0 + wc;
            #pragma unroll
            for (int j = 0; j < 4; ++j)
                crow[j * 16 + l15] = acc[i][j][r];
        }
    }
}

// ---------------------------------------------------------------------------
extern "C" void kernel_launch(void* const* d_in, const int* in_sizes, int n_in,
                              void* d_out, int out_size, void* d_ws, size_t ws_size,
                              hipStream_t stream) {
    const float* x   = (const float*)d_in[0];
    const float* Wq  = (const float*)d_in[1];
    const float* Wk  = (const float*)d_in[2];
    const float* Wv  = (const float*)d_in[3];
    const float* Wo  = (const float*)d_in[4];
    const float* cs  = (const float*)d_in[5];
    const float* sn  = (const float*)d_in[6];
    const int*   anc = (const int*)d_in[7];
    float* out = (float*)d_out;

    unsigned short* xb  = (unsigned short*)d_ws;
    unsigned short* Wtq = xb  + (size_t)2048 * 1024;
    unsigned short* Wtk = Wtq + (size_t)1024 * 1024;
    unsigned short* Wtv = Wtk + (size_t)1024 * 1024;
    unsigned short* Wto = Wtv + (size_t)1024 * 1024;
    unsigned short* qh  = Wto + (size_t)1024 * 1024;   // [H][S][64]
    unsigned short* kh  = qh  + (size_t)2048 * 1024;
    unsigned short* vh  = kh  + (size_t)2048 * 1024;
    unsigned short* att = vh  + (size_t)2048 * 1024;   // [S][H*D]

    prep<<<5120, 256, 0, stream>>>(x, xb, Wq, Wk, Wv, Wo, Wtq, Wtk, Wtv, Wto);
    gemm_qkv<<<dim3(24, 32), 256, 0, stream>>>(xb, Wtq, Wtk, Wtv,
                                               qh, kh, vh, cs, sn);
    attn_kernel<<<(S_LEN * NH) / 4, 256, 0, stream>>>(qh, kh, vh, anc, att);
    gemm_out<<<dim3(8, 32), 256, 0, stream>>>(att, Wto, out);
}

// Round 16
// 154.145 us; speedup vs baseline: 1.2940x; 1.0231x over previous
//
#include <hip/hip_runtime.h>
#include <hip/hip_bf16.h>

// KascadeReuseAttention  B=1, S=2048, DM=1024, H=16, D=64, T=16, NA=3
// Round-16 (base r15 = 157.7us): single change — gemm_out retiled
// 64x128/256-blocks (1 block/CU: zero co-residency, GLL barrier drains
// fully exposed) -> 64x64/512-blocks (2/CU: two K-loops interleave per CU,
// drains overlap per m114 co-scheduling). All else frozen:
//   prep (r8), qkv 64x128 GLL 768-block (r15), attn (r8 verbatim — local
//   optimum after 3 failed restructures: r7 dependent-address, r12 barrier,
//   r14 2-query ILP).
// Known budget: ~45us harness ws-poison fill (in timed path, immovable) +
// ~40us latency-bound attn + ~25 qkv + ~10 prep + out + gaps.

#define S_LEN 2048
#define DM 1024
#define NH 16
#define HD 64

typedef __bf16 bf16x8 __attribute__((ext_vector_type(8)));
typedef float f32x4 __attribute__((ext_vector_type(4)));

static __device__ __forceinline__ unsigned short f2bf(float f) {
    union { float f; unsigned int i; } un;
    un.f = f;
    unsigned int r = un.i + 0x7FFFu + ((un.i >> 16) & 1u);  // RNE
    return (unsigned short)(r >> 16);
}
static __device__ __forceinline__ float bfu2f(unsigned short u) {
    union { unsigned int i; float f; } un;
    un.i = ((unsigned int)u) << 16;
    return un.f;
}
static __device__ __forceinline__ float bflo(unsigned int u) {
    union { unsigned int i; float f; } un;
    un.i = u << 16;
    return un.f;
}
static __device__ __forceinline__ float bfhi(unsigned int u) {
    union { unsigned int i; float f; } un;
    un.i = u & 0xFFFF0000u;
    return un.f;
}

// async global->LDS, 16 B per lane; LDS dest = uniform base + lane*16.
static __device__ __forceinline__ void gll16(const unsigned short* g,
                                             unsigned short* l) {
    __builtin_amdgcn_global_load_lds(
        (const __attribute__((address_space(1))) unsigned int*)(uintptr_t)g,
        (__attribute__((address_space(3))) unsigned int*)(uintptr_t)l,
        16, 0, 0);
}

// ---------------------------------------------------------------------------
// prep: blocks [0,4096) transpose W* fp32->bf16 [n][k]; blocks [4096,5120)
// convert x fp32->bf16.
// ---------------------------------------------------------------------------
__global__ __launch_bounds__(256) void prep(
    const float* __restrict__ x, unsigned short* __restrict__ xb,
    const float* __restrict__ W0, const float* __restrict__ W1,
    const float* __restrict__ W2, const float* __restrict__ W3,
    unsigned short* __restrict__ T0, unsigned short* __restrict__ T1,
    unsigned short* __restrict__ T2, unsigned short* __restrict__ T3) {
    const int bx = blockIdx.x;
    if (bx < 4096) {
        const int z = bx >> 10, rem = bx & 1023;
        const float* W = (z == 0) ? W0 : (z == 1) ? W1 : (z == 2) ? W2 : W3;
        unsigned short* T = (z == 0) ? T0 : (z == 1) ? T1 : (z == 2) ? T2 : T3;
        __shared__ float t[32][33];
        const int bn = (rem & 31) * 32, bk = (rem >> 5) * 32;
        const int tx = threadIdx.x & 31, ty = threadIdx.x >> 5;
        #pragma unroll
        for (int m = 0; m < 4; ++m)
            t[ty + m * 8][tx] = W[(size_t)(bk + ty + m * 8) * 1024 + bn + tx];
        __syncthreads();
        #pragma unroll
        for (int m = 0; m < 4; ++m)
            T[(size_t)(bn + ty + m * 8) * 1024 + bk + tx] = f2bf(t[tx][ty + m * 8]);
    } else {
        const int i = (bx - 4096) * 2048 + threadIdx.x * 8;
        float4 f0 = *(const float4*)(x + i);
        float4 f1 = *(const float4*)(x + i + 4);
        ushort4 o0, o1;
        o0.x = f2bf(f0.x); o0.y = f2bf(f0.y); o0.z = f2bf(f0.z); o0.w = f2bf(f0.w);
        o1.x = f2bf(f1.x); o1.y = f2bf(f1.y); o1.z = f2bf(f1.z); o1.w = f2bf(f1.w);
        *(ushort4*)(xb + i) = o0;
        *(ushort4*)(xb + i + 4) = o1;
    }
}

// ---------------------------------------------------------------------------
// QKV GEMM (r15-verbatim): 64x128 tile, BK=32, grid (24,32) = 768 blocks
// (3/CU, no tail), global_load_lds width-16 staging. Fused RoPE epilogue,
// head-major bf16 out [H][S][64].
// ---------------------------------------------------------------------------
__global__ __launch_bounds__(256) void gemm_qkv(
    const unsigned short* __restrict__ xb,
    const unsigned short* __restrict__ Wtq, const unsigned short* __restrict__ Wtk,
    const unsigned short* __restrict__ Wtv,
    unsigned short* __restrict__ qh, unsigned short* __restrict__ kh,
    unsigned short* __restrict__ vh,
    const float* __restrict__ cs, const float* __restrict__ sn) {
    __shared__ __align__(16) unsigned short Al[64 * 32];
    __shared__ __align__(16) unsigned short Bl[128 * 32];
    const int tid = threadIdx.x;
    const int nb = blockIdx.x >> 3;
    const unsigned short* __restrict__ Bt = (nb == 0) ? Wtq : (nb == 1) ? Wtk : Wtv;
    unsigned short* __restrict__ OUT = (nb == 0) ? qh : (nb == 1) ? kh : vh;
    const int col0 = (blockIdx.x & 7) * 128;
    const int row0 = blockIdx.y * 64;
    const int lane = tid & 63, wvi = tid >> 6;
    const int wr = (wvi >> 1) * 32, wc = (wvi & 1) * 64;
    const int l15 = lane & 15, quad = lane >> 4;

    const int grow = lane >> 2;            // 0..15
    const int gkc = (lane & 3) * 8;        // element offset within row
    const unsigned short* gA = xb + (size_t)(row0 + wvi * 16 + grow) * 1024 + gkc;
    const unsigned short* gB = Bt + (size_t)(col0 + wvi * 32 + grow) * 1024 + gkc;
    unsigned short* lA = Al + (wvi * 16) * 32;   // wave-uniform LDS base
    unsigned short* lB = Bl + (wvi * 32) * 32;

    f32x4 acc[2][4] = {};
    for (int k0 = 0; k0 < 1024; k0 += 32) {
        __syncthreads();  // prior iter's ds_reads complete before overwrite
        gll16(gA + k0, lA);                       // A: 64 rows total
        gll16(gB + k0, lB);                       // B: 128 rows total
        gll16(gB + 16 * 1024 + k0, lB + 16 * 32);
        __syncthreads();  // drains vmcnt(0): GLL data landed
        bf16x8 af[2], bfr[4];
        #pragma unroll
        for (int i = 0; i < 2; ++i)
            af[i] = *(const bf16x8*)&Al[(wr + i * 16 + l15) * 32 + quad * 8];
        #pragma unroll
        for (int j = 0; j < 4; ++j)
            bfr[j] = *(const bf16x8*)&Bl[(wc + j * 16 + l15) * 32 + quad * 8];
        #pragma unroll
        for (int i = 0; i < 2; ++i)
            #pragma unroll
            for (int j = 0; j < 4; ++j)
                acc[i][j] = __builtin_amdgcn_mfma_f32_16x16x32_bf16(
                    af[i], bfr[j], acc[i][j], 0, 0, 0);
    }

    // epilogue: wave's 64 cols = one head; fused RoPE; head-major store
    const int hh = ((blockIdx.x & 7) << 1) + (wc >> 6);
    const bool dorope = (nb != 2);
    #pragma unroll
    for (int i = 0; i < 2; ++i) {
        const int rowb = row0 + wr + i * 16 + quad * 4;
        #pragma unroll
        for (int r = 0; r < 4; ++r) {
            const int s = rowb + r;
            float v0 = acc[i][0][r], v1 = acc[i][1][r];
            float v2 = acc[i][2][r], v3 = acc[i][3][r];
            if (dorope) {
                float c0 = cs[s * 32 + l15],      s0 = sn[s * 32 + l15];
                float c1 = cs[s * 32 + 16 + l15], s1 = sn[s * 32 + 16 + l15];
                float lo0 = v0 * c0 - v2 * s0;
                float hi0 = v2 * c0 + v0 * s0;
                float lo1 = v1 * c1 - v3 * s1;
                float hi1 = v3 * c1 + v1 * s1;
                v0 = lo0; v1 = lo1; v2 = hi0; v3 = hi1;
            }
            unsigned short* op = OUT + (size_t)hh * (S_LEN * 64) + (size_t)s * 64 + l15;
            op[0]  = f2bf(v0);
            op[16] = f2bf(v1);
            op[32] = f2bf(v2);
            op[48] = f2bf(v3);
        }
    }
}

// ---------------------------------------------------------------------------
// Attention (r8-verbatim, frozen): one wave per (h,q). Wave-private LDS
// slices; same-address broadcast ds_reads; phase-4 addresses from ts
// (written phase 1) so v-loads issue under the softmax chain.
// ---------------------------------------------------------------------------
__global__ __launch_bounds__(256) void attn_kernel(
    const unsigned short* __restrict__ qh, const unsigned short* __restrict__ kh,
    const unsigned short* __restrict__ vh, const int* __restrict__ anc,
    unsigned short* __restrict__ att) {
    __shared__ __align__(16) float qs[4][64];
    __shared__ __align__(16) int   ts[4][64];
    __shared__ __align__(16) float ws[4][64];
    const int w4 = threadIdx.x >> 6;
    const int lane = threadIdx.x & 63;
    const int wid = (blockIdx.x << 2) + w4;
    const int h = wid >> 11;
    const int qi = wid & 2047;
    const size_t hb = (size_t)h * (S_LEN * 64);

    const float q_own = bfu2f(qh[hb + (size_t)qi * 64 + lane]);
    const int slot = lane >> 4;
    const int tile = (slot < 3) ? anc[((size_t)h * S_LEN + qi) * 3 + slot]
                                : (qi >> 4);
    const int tok_own = tile * 16 + (lane & 15);
    qs[w4][lane] = q_own;
    ts[w4][lane] = tok_own;

    const int c = lane & 3;
    const int t = lane >> 2;
    float qv[16];
    #pragma unroll
    for (int r = 0; r < 4; ++r) {
        float4 f = *(const float4*)&qs[w4][c * 16 + r * 4];
        qv[r * 4 + 0] = f.x; qv[r * 4 + 1] = f.y;
        qv[r * 4 + 2] = f.z; qv[r * 4 + 3] = f.w;
    }

    #pragma unroll
    for (int p = 0; p < 4; ++p) {
        const int tk = ts[w4][p * 16 + t];
        const unsigned short* kp = kh + hb + (size_t)tk * 64 + c * 16;
        const uint4 k0 = *(const uint4*)kp;
        const uint4 k1 = *(const uint4*)(kp + 8);
        float part;
        part = bflo(k0.x) * qv[0];
        part = fmaf(bfhi(k0.x), qv[1], part);
        part = fmaf(bflo(k0.y), qv[2], part);
        part = fmaf(bfhi(k0.y), qv[3], part);
        part = fmaf(bflo(k0.z), qv[4], part);
        part = fmaf(bfhi(k0.z), qv[5], part);
        part = fmaf(bflo(k0.w), qv[6], part);
        part = fmaf(bfhi(k0.w), qv[7], part);
        part = fmaf(bflo(k1.x), qv[8], part);
        part = fmaf(bfhi(k1.x), qv[9], part);
        part = fmaf(bflo(k1.y), qv[10], part);
        part = fmaf(bfhi(k1.y), qv[11], part);
        part = fmaf(bflo(k1.z), qv[12], part);
        part = fmaf(bfhi(k1.z), qv[13], part);
        part = fmaf(bflo(k1.w), qv[14], part);
        part = fmaf(bfhi(k1.w), qv[15], part);
        part += __shfl_xor(part, 1, 64);
        part += __shfl_xor(part, 2, 64);
        if (c == 0) ws[w4][p * 16 + t] = part;
    }

    float logit = ws[w4][lane];
    const bool fut = tok_own > qi;
    logit = fut ? -1e30f : logit * 0.125f;

    float m = logit;
    #pragma unroll
    for (int off = 32; off >= 1; off >>= 1)
        m = fmaxf(m, __shfl_xor(m, off, 64));
    const float e = fut ? 0.f : __expf(logit - m);
    float ssum = e;
    #pragma unroll
    for (int off = 32; off >= 1; off >>= 1)
        ssum += __shfl_xor(ssum, off, 64);
    ws[w4][lane] = e / ssum;

    const unsigned short* vb = vh + hb + lane;
    float out = 0.f;
    #pragma unroll
    for (int kk = 0; kk < 64; kk += 8) {
        const int4 ta = *(const int4*)&ts[w4][kk];
        const int4 tb = *(const int4*)&ts[w4][kk + 4];
        const float v0 = bfu2f(vb[(size_t)ta.x * 64]);
        const float v1 = bfu2f(vb[(size_t)ta.y * 64]);
        const float v2 = bfu2f(vb[(size_t)ta.z * 64]);
        const float v3 = bfu2f(vb[(size_t)ta.w * 64]);
        const float v4 = bfu2f(vb[(size_t)tb.x * 64]);
        const float v5 = bfu2f(vb[(size_t)tb.y * 64]);
        const float v6 = bfu2f(vb[(size_t)tb.z * 64]);
        const float v7 = bfu2f(vb[(size_t)tb.w * 64]);
        const float4 wa = *(const float4*)&ws[w4][kk];
        const float4 wb = *(const float4*)&ws[w4][kk + 4];
        out = fmaf(wa.x, v0, out);
        out = fmaf(wa.y, v1, out);
        out = fmaf(wa.z, v2, out);
        out = fmaf(wa.w, v3, out);
        out = fmaf(wb.x, v4, out);
        out = fmaf(wb.y, v5, out);
        out = fmaf(wb.z, v6, out);
        out = fmaf(wb.w, v7, out);
    }
    att[(size_t)qi * DM + h * HD + lane] = f2bf(out);
}

// ---------------------------------------------------------------------------
// Out GEMM: 64x64 tile, grid (16,32) = 512 blocks = 2/CU (was 256 = 1/CU,
// no co-residency -> GLL drains exposed). Wave tile 32x32; 2 GLL + 4 MFMA
// per wave per K-iter.
// ---------------------------------------------------------------------------
__global__ __launch_bounds__(256) void gemm_out(
    const unsigned short* __restrict__ A, const unsigned short* __restrict__ Bt,
    float* __restrict__ C) {
    __shared__ __align__(16) unsigned short Al[64 * 32];
    __shared__ __align__(16) unsigned short Bl[64 * 32];
    const int tid = threadIdx.x;
    const int col0 = blockIdx.x * 64;
    const int row0 = blockIdx.y * 64;
    const int lane = tid & 63, wvi = tid >> 6;
    const int wr = (wvi >> 1) * 32, wc = (wvi & 1) * 32;
    const int l15 = lane & 15, quad = lane >> 4;

    const int grow = lane >> 2;
    const int gkc = (lane & 3) * 8;
    const unsigned short* gA = A + (size_t)(row0 + wvi * 16 + grow) * 1024 + gkc;
    const unsigned short* gB = Bt + (size_t)(col0 + wvi * 16 + grow) * 1024 + gkc;
    unsigned short* lA = Al + (wvi * 16) * 32;   // wave-uniform
    unsigned short* lB = Bl + (wvi * 16) * 32;

    f32x4 acc[2][2] = {};
    for (int k0 = 0; k0 < 1024; k0 += 32) {
        __syncthreads();
        gll16(gA + k0, lA);                       // A: 64 rows total
        gll16(gB + k0, lB);                       // B: 64 rows total
        __syncthreads();
        bf16x8 af[2], bfr[2];
        #pragma unroll
        for (int i = 0; i < 2; ++i)
            af[i] = *(const bf16x8*)&Al[(wr + i * 16 + l15) * 32 + quad * 8];
        #pragma unroll
        for (int j = 0; j < 2; ++j)
            bfr[j] = *(const bf16x8*)&Bl[(wc + j * 16 + l15) * 32 + quad * 8];
        #pragma unroll
        for (int i = 0; i < 2; ++i)
            #pragma unroll
            for (int j = 0; j < 2; ++j)
                acc[i][j] = __builtin_amdgcn_mfma_f32_16x16x32_bf16(
                    af[i], bfr[j], acc[i][j], 0, 0, 0);
    }
    #pragma unroll
    for (int i = 0; i < 2; ++i) {
        const int rowb = row0 + wr + i * 16 + quad * 4;
        #pragma unroll
        for (int r = 0; r < 4; ++r) {
            float* crow = C + (size_t)(rowb + r) * 1024 + col0 + wc;
            #pragma unroll
            for (int j = 0; j < 2; ++j)
                crow[j * 16 + l15] = acc[i][j][r];
        }
    }
}

// ---------------------------------------------------------------------------
extern "C" void kernel_launch(void* const* d_in, const int* in_sizes, int n_in,
                              void* d_out, int out_size, void* d_ws, size_t ws_size,
                              hipStream_t stream) {
    const float* x   = (const float*)d_in[0];
    const float* Wq  = (const float*)d_in[1];
    const float* Wk  = (const float*)d_in[2];
    const float* Wv  = (const float*)d_in[3];
    const float* Wo  = (const float*)d_in[4];
    const float* cs  = (const float*)d_in[5];
    const float* sn  = (const float*)d_in[6];
    const int*   anc = (const int*)d_in[7];
    float* out = (float*)d_out;

    unsigned short* xb  = (unsigned short*)d_ws;
    unsigned short* Wtq = xb  + (size_t)2048 * 1024;
    unsigned short* Wtk = Wtq + (size_t)1024 * 1024;
    unsigned short* Wtv = Wtk + (size_t)1024 * 1024;
    unsigned short* Wto = Wtv + (size_t)1024 * 1024;
    unsigned short* qh  = Wto + (size_t)1024 * 1024;   // [H][S][64]
    unsigned short* kh  = qh  + (size_t)2048 * 1024;
    unsigned short* vh  = kh  + (size_t)2048 * 1024;
    unsigned short* att = vh  + (size_t)2048 * 1024;   // [S][H*D]

    prep<<<5120, 256, 0, stream>>>(x, xb, Wq, Wk, Wv, Wo, Wtq, Wtk, Wtv, Wto);
    gemm_qkv<<<dim3(24, 32), 256, 0, stream>>>(xb, Wtq, Wtk, Wtv,
                                               qh, kh, vh, cs, sn);
    attn_kernel<<<(S_LEN * NH) / 4, 256, 0, stream>>>(qh, kh, vh, anc, att);
    gemm_out<<<dim3(16, 32), 256, 0, stream>>>(att, Wto, out);
}